// Round 1
// baseline (6076.710 us; speedup 1.0000x reference)
//
#include <hip/hip_runtime.h>

#define TW    10000
#define EMBD  100
#define SEQ   80
#define U     512
#define BATCH 2048
#define RPB   16
#define NBLK  (BATCH / RPB)   // 128 blocks

typedef short short8 __attribute__((ext_vector_type(8)));
typedef float f32x4 __attribute__((ext_vector_type(4)));

static __device__ __forceinline__ unsigned short f2bf(float f){
  unsigned int u = __float_as_uint(f);
  u += 0x7fffu + ((u >> 16) & 1u);   // RNE
  return (unsigned short)(u >> 16);
}
static __device__ __forceinline__ float bf2f(unsigned short h){
  return __uint_as_float(((unsigned int)h) << 16);
}
static __device__ __forceinline__ float fast_tanh(float x){
  float e = __expf(2.0f * x);        // inf-safe: saturates to +-1
  return 1.0f - 2.0f / (e + 1.0f);
}

// ---------------- proj[w][n] = b0[n] + sum_e emb[w][e] * Wx0[e][n] ----------------
__global__ void proj_kernel(const float* __restrict__ emb, const float* __restrict__ Wx0,
                            const float* __restrict__ b0, float* __restrict__ proj){
  __shared__ float es[16][EMBD];
  const int w0 = blockIdx.x * 16;
  for (int i = threadIdx.x; i < 16 * EMBD; i += 256)
    es[i / EMBD][i % EMBD] = emb[(size_t)w0 * EMBD + i];
  __syncthreads();
  const int n = threadIdx.x;   // cols n and n+256
  float accA[16], accB[16];
#pragma unroll
  for (int wi = 0; wi < 16; ++wi){ accA[wi] = 0.0f; accB[wi] = 0.0f; }
  for (int e = 0; e < EMBD; ++e){
    const float wv0 = Wx0[(size_t)e * U + n];
    const float wv1 = Wx0[(size_t)e * U + n + 256];
#pragma unroll
    for (int wi = 0; wi < 16; ++wi){
      accA[wi] += es[wi][e] * wv0;
      accB[wi] += es[wi][e] * wv1;
    }
  }
  const float bb0 = b0[n], bb1 = b0[n + 256];
  for (int wi = 0; wi < 16; ++wi){
    proj[(size_t)(w0 + wi) * U + n]       = accA[wi] + bb0;
    proj[(size_t)(w0 + wi) * U + n + 256] = accB[wi] + bb1;
  }
}

// ---------------- dst[n][kOff + k] = bf16(src[k][n]),  src is [K][N] f32 ----------------
__global__ void transpose_bf16(const float* __restrict__ src, unsigned short* __restrict__ dst,
                               int K, int N, int dstLd, int kOff){
  const int idx = blockIdx.x * 256 + threadIdx.x;
  if (idx >= K * N) return;
  const int k = idx % K, n = idx / K;
  dst[(size_t)n * dstLd + kOff + k] = f2bf(src[(size_t)k * N + n]);
}

// ---------------- persistent per-block RNN: R rows through all 80 steps ----------------
__global__ __launch_bounds__(512, 2)
void rnn_persist(const int* __restrict__ tokens,
                 const float* __restrict__ proj,
                 const unsigned short* __restrict__ Wh0t,
                 const unsigned short* __restrict__ W1t,
                 const unsigned short* __restrict__ W2t,
                 const float* __restrict__ b1,
                 const float* __restrict__ b2,
                 const float* __restrict__ Wout,
                 const float* __restrict__ bout,
                 float* __restrict__ out)
{
  __shared__ unsigned short st0[RPB * U];   // 16 KiB each, bf16, XOR-swizzled
  __shared__ unsigned short st1[RPB * U];
  __shared__ unsigned short st2[RPB * U];

  const int tid = threadIdx.x;
  for (int i = tid; i < RPB * U; i += 512){ st0[i] = 0; st1[i] = 0; st2[i] = 0; }
  __syncthreads();

  const int lane = tid & 63;
  const int wid  = tid >> 6;          // 8 waves, 64 output cols each
  const int l15  = lane & 15;
  const int khi  = lane >> 4;         // 0..3
  const int n0   = wid * 64;
  const int rowbase = blockIdx.x * RPB;

  // A-frag LDS elem address: row l15, k = k0 + khi*8 + j ; swizzle bits 3..5 by row
  const int aBase = l15 * U + khi * 8;
  const int aSwz  = (l15 & 7) << 3;

  const unsigned short* bp0[4];
  const unsigned short* bp1[4];
  const unsigned short* bp2[4];
  float b1v[4], b2v[4];
#pragma unroll
  for (int nf = 0; nf < 4; ++nf){
    const int n = n0 + nf * 16 + l15;
    bp0[nf] = Wh0t + (size_t)n * U       + khi * 8;
    bp1[nf] = W1t  + (size_t)n * (2 * U) + khi * 8;
    bp2[nf] = W2t  + (size_t)n * (2 * U) + khi * 8;
    b1v[nf] = b1[n];
    b2v[nf] = b2[n];
  }

  f32x4 acc[4];

  for (int t = 0; t < SEQ; ++t){
    // ---------- layer 0: o0 = tanh(proj[tok] + s0 @ Wh0) ----------
#pragma unroll
    for (int nf = 0; nf < 4; ++nf) acc[nf] = 0.0f;
#pragma unroll 4
    for (int ks = 0; ks < U / 32; ++ks){
      const int k0 = ks * 32;
      short8 a = *reinterpret_cast<const short8*>(&st0[(aBase + k0) ^ aSwz]);
#pragma unroll
      for (int nf = 0; nf < 4; ++nf){
        short8 b = *reinterpret_cast<const short8*>(bp0[nf] + k0);
        acc[nf] = __builtin_amdgcn_mfma_f32_16x16x32_bf16(a, b, acc[nf], 0, 0, 0);
      }
    }
    int tok[4];
#pragma unroll
    for (int j = 0; j < 4; ++j)
      tok[j] = tokens[(size_t)(rowbase + khi * 4 + j) * SEQ + t];
    __syncthreads();                 // everyone done reading st0
#pragma unroll
    for (int nf = 0; nf < 4; ++nf){
      const int col = n0 + nf * 16 + l15;
#pragma unroll
      for (int j = 0; j < 4; ++j){
        const int rr = khi * 4 + j;
        const float z = acc[nf][j] + proj[(size_t)tok[j] * U + col];
        st0[(rr * U + col) ^ ((rr & 7) << 3)] = f2bf(fast_tanh(z));
      }
    }
    __syncthreads();

    // ---------- layer 1: o1 = tanh([o0 | s1] @ [Wx1;Wh1] + b1) ----------
#pragma unroll
    for (int nf = 0; nf < 4; ++nf) acc[nf] = 0.0f;
#pragma unroll 4
    for (int ks = 0; ks < U / 32; ++ks){
      const int k0 = ks * 32;
      short8 a = *reinterpret_cast<const short8*>(&st0[(aBase + k0) ^ aSwz]);
#pragma unroll
      for (int nf = 0; nf < 4; ++nf){
        short8 b = *reinterpret_cast<const short8*>(bp1[nf] + k0);
        acc[nf] = __builtin_amdgcn_mfma_f32_16x16x32_bf16(a, b, acc[nf], 0, 0, 0);
      }
    }
#pragma unroll 4
    for (int ks = 0; ks < U / 32; ++ks){
      const int k0 = ks * 32;
      short8 a = *reinterpret_cast<const short8*>(&st1[(aBase + k0) ^ aSwz]);
#pragma unroll
      for (int nf = 0; nf < 4; ++nf){
        short8 b = *reinterpret_cast<const short8*>(bp1[nf] + U + k0);
        acc[nf] = __builtin_amdgcn_mfma_f32_16x16x32_bf16(a, b, acc[nf], 0, 0, 0);
      }
    }
    __syncthreads();
#pragma unroll
    for (int nf = 0; nf < 4; ++nf){
      const int col = n0 + nf * 16 + l15;
#pragma unroll
      for (int j = 0; j < 4; ++j){
        const int rr = khi * 4 + j;
        st1[(rr * U + col) ^ ((rr & 7) << 3)] = f2bf(fast_tanh(acc[nf][j] + b1v[nf]));
      }
    }
    __syncthreads();

    // ---------- layer 2: o2 = tanh([o1 | s2] @ [Wx2;Wh2] + b2) ----------
#pragma unroll
    for (int nf = 0; nf < 4; ++nf) acc[nf] = 0.0f;
#pragma unroll 4
    for (int ks = 0; ks < U / 32; ++ks){
      const int k0 = ks * 32;
      short8 a = *reinterpret_cast<const short8*>(&st1[(aBase + k0) ^ aSwz]);
#pragma unroll
      for (int nf = 0; nf < 4; ++nf){
        short8 b = *reinterpret_cast<const short8*>(bp2[nf] + k0);
        acc[nf] = __builtin_amdgcn_mfma_f32_16x16x32_bf16(a, b, acc[nf], 0, 0, 0);
      }
    }
#pragma unroll 4
    for (int ks = 0; ks < U / 32; ++ks){
      const int k0 = ks * 32;
      short8 a = *reinterpret_cast<const short8*>(&st2[(aBase + k0) ^ aSwz]);
#pragma unroll
      for (int nf = 0; nf < 4; ++nf){
        short8 b = *reinterpret_cast<const short8*>(bp2[nf] + U + k0);
        acc[nf] = __builtin_amdgcn_mfma_f32_16x16x32_bf16(a, b, acc[nf], 0, 0, 0);
      }
    }
    __syncthreads();
#pragma unroll
    for (int nf = 0; nf < 4; ++nf){
      const int col = n0 + nf * 16 + l15;
#pragma unroll
      for (int j = 0; j < 4; ++j){
        const int rr = khi * 4 + j;
        st2[(rr * U + col) ^ ((rr & 7) << 3)] = f2bf(fast_tanh(acc[nf][j] + b2v[nf]));
      }
    }
    __syncthreads();
  }

  // ---------- output: sigmoid(s2 @ Wout + bout) ----------
  const int r = tid >> 5;          // 16 rows, 32 threads each
  const int m = tid & 31;
  float v = 0.0f;
  for (int jj = 0; jj < 16; ++jj){
    const int n = m + jj * 32;
    v += bf2f(st2[(r * U + n) ^ ((r & 7) << 3)]) * Wout[n];
  }
#pragma unroll
  for (int off = 16; off > 0; off >>= 1)
    v += __shfl_down(v, off, 32);
  if (m == 0)
    out[rowbase + r] = 1.0f / (1.0f + __expf(-(v + bout[0])));
}

extern "C" void kernel_launch(void* const* d_in, const int* in_sizes, int n_in,
                              void* d_out, int out_size, void* d_ws, size_t ws_size,
                              hipStream_t stream){
  (void)in_sizes; (void)n_in; (void)out_size; (void)ws_size;
  const int*   tokens = (const int*)  d_in[0];
  const float* emb  = (const float*)d_in[1];
  const float* Wx0  = (const float*)d_in[2];
  const float* Wh0  = (const float*)d_in[3];
  const float* b0   = (const float*)d_in[4];
  const float* Wx1  = (const float*)d_in[5];
  const float* Wh1  = (const float*)d_in[6];
  const float* b1   = (const float*)d_in[7];
  const float* Wx2  = (const float*)d_in[8];
  const float* Wh2  = (const float*)d_in[9];
  const float* b2   = (const float*)d_in[10];
  const float* Wout = (const float*)d_in[11];
  const float* bout = (const float*)d_in[12];

  char* ws = (char*)d_ws;
  float* proj = (float*)ws;                                   // 10000*512*4  = 20.48 MB
  unsigned short* Wh0t = (unsigned short*)(ws + (size_t)TW * U * 4);
  unsigned short* W1t  = Wh0t + (size_t)U * U;                // [512][1024]
  unsigned short* W2t  = W1t  + (size_t)U * 2 * U;

  proj_kernel<<<TW / 16, 256, 0, stream>>>(emb, Wx0, b0, proj);
  const int tblk = (U * U + 255) / 256;
  transpose_bf16<<<tblk, 256, 0, stream>>>(Wh0, Wh0t, U, U, U,     0);
  transpose_bf16<<<tblk, 256, 0, stream>>>(Wx1, W1t,  U, U, 2 * U, 0);
  transpose_bf16<<<tblk, 256, 0, stream>>>(Wh1, W1t,  U, U, 2 * U, U);
  transpose_bf16<<<tblk, 256, 0, stream>>>(Wx2, W2t,  U, U, 2 * U, 0);
  transpose_bf16<<<tblk, 256, 0, stream>>>(Wh2, W2t,  U, U, 2 * U, U);

  rnn_persist<<<NBLK, 512, 0, stream>>>(tokens, proj, Wh0t, W1t, W2t,
                                        b1, b2, Wout, bout, (float*)d_out);
}

// Round 2
// 5880.904 us; speedup vs baseline: 1.0333x; 1.0333x over previous
//
#include <hip/hip_runtime.h>

#define TW    10000
#define EMBD  100
#define SEQ   80
#define U     512
#define BATCH 2048
#define RPB   16
#define NBLK  (BATCH / RPB)   // 128 blocks
#define NTHR  1024            // 16 waves/block -> 4 waves/SIMD

typedef short short8 __attribute__((ext_vector_type(8)));
typedef float f32x4 __attribute__((ext_vector_type(4)));

static __device__ __forceinline__ unsigned short f2bf(float f){
  unsigned int u = __float_as_uint(f);
  u += 0x7fffu + ((u >> 16) & 1u);   // RNE
  return (unsigned short)(u >> 16);
}
static __device__ __forceinline__ float bf2f(unsigned short h){
  return __uint_as_float(((unsigned int)h) << 16);
}
static __device__ __forceinline__ float fast_tanh(float x){
  float e = __expf(2.0f * x);        // inf-safe: saturates to +-1
  return 1.0f - 2.0f / (e + 1.0f);
}

// ---------------- proj[w][n] = b0[n] + sum_e emb[w][e] * Wx0[e][n] ----------------
__global__ void proj_kernel(const float* __restrict__ emb, const float* __restrict__ Wx0,
                            const float* __restrict__ b0, float* __restrict__ proj){
  __shared__ float es[16][EMBD];
  const int w0 = blockIdx.x * 16;
  for (int i = threadIdx.x; i < 16 * EMBD; i += 256)
    es[i / EMBD][i % EMBD] = emb[(size_t)w0 * EMBD + i];
  __syncthreads();
  const int n = threadIdx.x;   // cols n and n+256
  float accA[16], accB[16];
#pragma unroll
  for (int wi = 0; wi < 16; ++wi){ accA[wi] = 0.0f; accB[wi] = 0.0f; }
  for (int e = 0; e < EMBD; ++e){
    const float wv0 = Wx0[(size_t)e * U + n];
    const float wv1 = Wx0[(size_t)e * U + n + 256];
#pragma unroll
    for (int wi = 0; wi < 16; ++wi){
      accA[wi] += es[wi][e] * wv0;
      accB[wi] += es[wi][e] * wv1;
    }
  }
  const float bb0 = b0[n], bb1 = b0[n + 256];
  for (int wi = 0; wi < 16; ++wi){
    proj[(size_t)(w0 + wi) * U + n]       = accA[wi] + bb0;
    proj[(size_t)(w0 + wi) * U + n + 256] = accB[wi] + bb1;
  }
}

// ---------------- dst[n][kOff + k] = bf16(src[k][n]),  src is [K][N] f32 ----------------
__global__ void transpose_bf16(const float* __restrict__ src, unsigned short* __restrict__ dst,
                               int K, int N, int dstLd, int kOff){
  const int idx = blockIdx.x * 256 + threadIdx.x;
  if (idx >= K * N) return;
  const int k = idx % K, n = idx / K;
  dst[(size_t)n * dstLd + kOff + k] = f2bf(src[(size_t)k * N + n]);
}

// ---------------- persistent per-block RNN: 16 rows through all 80 steps ----------------
__global__ __launch_bounds__(NTHR, 4)
void rnn_persist(const int* __restrict__ tokens,
                 const float* __restrict__ proj,
                 const unsigned short* __restrict__ Wh0t,
                 const unsigned short* __restrict__ W1t,
                 const unsigned short* __restrict__ W2t,
                 const float* __restrict__ b1,
                 const float* __restrict__ b2,
                 const float* __restrict__ Wout,
                 const float* __restrict__ bout,
                 float* __restrict__ out)
{
  __shared__ unsigned short st0[RPB * U];   // 16 KiB each, bf16, XOR-swizzled
  __shared__ unsigned short st1[RPB * U];
  __shared__ unsigned short st2[RPB * U];

  const int tid = threadIdx.x;
  for (int i = tid; i < RPB * U; i += NTHR){ st0[i] = 0; st1[i] = 0; st2[i] = 0; }
  __syncthreads();

  const int lane = tid & 63;
  const int wid  = tid >> 6;          // 16 waves, 32 output cols each
  const int l15  = lane & 15;
  const int khi  = lane >> 4;         // 0..3
  const int n0   = wid * 32;
  const int rowbase = blockIdx.x * RPB;

  // A-frag LDS elem address: row l15, k = k0 + khi*8 + j ; swizzle bits 3..5 by row
  const int aBase = l15 * U + khi * 8;
  const int aSwz  = (l15 & 7) << 3;

  const unsigned short* bp0[2];
  const unsigned short* bp1[2];
  const unsigned short* bp2[2];
  float b1v[2], b2v[2];
#pragma unroll
  for (int nf = 0; nf < 2; ++nf){
    const int n = n0 + nf * 16 + l15;
    bp0[nf] = Wh0t + (size_t)n * U       + khi * 8;
    bp1[nf] = W1t  + (size_t)n * (2 * U) + khi * 8;
    bp2[nf] = W2t  + (size_t)n * (2 * U) + khi * 8;
    b1v[nf] = b1[n];
    b2v[nf] = b2[n];
  }

  f32x4 acc[2];

  for (int t = 0; t < SEQ; ++t){
    // ---------- layer 0: o0 = tanh(proj[tok] + s0 @ Wh0) ----------
#pragma unroll
    for (int nf = 0; nf < 2; ++nf) acc[nf] = 0.0f;
#pragma unroll 8
    for (int ks = 0; ks < U / 32; ++ks){
      const int k0 = ks * 32;
      short8 a = *reinterpret_cast<const short8*>(&st0[(aBase + k0) ^ aSwz]);
#pragma unroll
      for (int nf = 0; nf < 2; ++nf){
        short8 b = *reinterpret_cast<const short8*>(bp0[nf] + k0);
        acc[nf] = __builtin_amdgcn_mfma_f32_16x16x32_bf16(a, b, acc[nf], 0, 0, 0);
      }
    }
    int tok[4];
#pragma unroll
    for (int j = 0; j < 4; ++j)
      tok[j] = tokens[(size_t)(rowbase + khi * 4 + j) * SEQ + t];
    __syncthreads();                 // everyone done reading st0
#pragma unroll
    for (int nf = 0; nf < 2; ++nf){
      const int col = n0 + nf * 16 + l15;
#pragma unroll
      for (int j = 0; j < 4; ++j){
        const int rr = khi * 4 + j;
        const float z = acc[nf][j] + proj[(size_t)tok[j] * U + col];
        st0[(rr * U + col) ^ ((rr & 7) << 3)] = f2bf(fast_tanh(z));
      }
    }
    __syncthreads();

    // ---------- layer 1: o1 = tanh([o0 | s1] @ [Wx1;Wh1] + b1) ----------
#pragma unroll
    for (int nf = 0; nf < 2; ++nf) acc[nf] = 0.0f;
#pragma unroll 8
    for (int ks = 0; ks < U / 32; ++ks){
      const int k0 = ks * 32;
      short8 a = *reinterpret_cast<const short8*>(&st0[(aBase + k0) ^ aSwz]);
#pragma unroll
      for (int nf = 0; nf < 2; ++nf){
        short8 b = *reinterpret_cast<const short8*>(bp1[nf] + k0);
        acc[nf] = __builtin_amdgcn_mfma_f32_16x16x32_bf16(a, b, acc[nf], 0, 0, 0);
      }
    }
#pragma unroll 8
    for (int ks = 0; ks < U / 32; ++ks){
      const int k0 = ks * 32;
      short8 a = *reinterpret_cast<const short8*>(&st1[(aBase + k0) ^ aSwz]);
#pragma unroll
      for (int nf = 0; nf < 2; ++nf){
        short8 b = *reinterpret_cast<const short8*>(bp1[nf] + U + k0);
        acc[nf] = __builtin_amdgcn_mfma_f32_16x16x32_bf16(a, b, acc[nf], 0, 0, 0);
      }
    }
    __syncthreads();
#pragma unroll
    for (int nf = 0; nf < 2; ++nf){
      const int col = n0 + nf * 16 + l15;
#pragma unroll
      for (int j = 0; j < 4; ++j){
        const int rr = khi * 4 + j;
        st1[(rr * U + col) ^ ((rr & 7) << 3)] = f2bf(fast_tanh(acc[nf][j] + b1v[nf]));
      }
    }
    __syncthreads();

    // ---------- layer 2: o2 = tanh([o1 | s2] @ [Wx2;Wh2] + b2) ----------
#pragma unroll
    for (int nf = 0; nf < 2; ++nf) acc[nf] = 0.0f;
#pragma unroll 8
    for (int ks = 0; ks < U / 32; ++ks){
      const int k0 = ks * 32;
      short8 a = *reinterpret_cast<const short8*>(&st1[(aBase + k0) ^ aSwz]);
#pragma unroll
      for (int nf = 0; nf < 2; ++nf){
        short8 b = *reinterpret_cast<const short8*>(bp2[nf] + k0);
        acc[nf] = __builtin_amdgcn_mfma_f32_16x16x32_bf16(a, b, acc[nf], 0, 0, 0);
      }
    }
#pragma unroll 8
    for (int ks = 0; ks < U / 32; ++ks){
      const int k0 = ks * 32;
      short8 a = *reinterpret_cast<const short8*>(&st2[(aBase + k0) ^ aSwz]);
#pragma unroll
      for (int nf = 0; nf < 2; ++nf){
        short8 b = *reinterpret_cast<const short8*>(bp2[nf] + U + k0);
        acc[nf] = __builtin_amdgcn_mfma_f32_16x16x32_bf16(a, b, acc[nf], 0, 0, 0);
      }
    }
    __syncthreads();
#pragma unroll
    for (int nf = 0; nf < 2; ++nf){
      const int col = n0 + nf * 16 + l15;
#pragma unroll
      for (int j = 0; j < 4; ++j){
        const int rr = khi * 4 + j;
        st2[(rr * U + col) ^ ((rr & 7) << 3)] = f2bf(fast_tanh(acc[nf][j] + b2v[nf]));
      }
    }
    __syncthreads();
  }

  // ---------- output: sigmoid(s2 @ Wout + bout), one wave per row ----------
  if (wid < RPB){
    const int r = wid;
    float v = 0.0f;
#pragma unroll
    for (int jj = 0; jj < 8; ++jj){
      const int n = lane + jj * 64;
      v += bf2f(st2[(r * U + n) ^ ((r & 7) << 3)]) * Wout[n];
    }
#pragma unroll
    for (int off = 32; off > 0; off >>= 1)
      v += __shfl_down(v, off, 64);
    if (lane == 0)
      out[rowbase + r] = 1.0f / (1.0f + __expf(-(v + bout[0])));
  }
}

extern "C" void kernel_launch(void* const* d_in, const int* in_sizes, int n_in,
                              void* d_out, int out_size, void* d_ws, size_t ws_size,
                              hipStream_t stream){
  (void)in_sizes; (void)n_in; (void)out_size; (void)ws_size;
  const int*   tokens = (const int*)  d_in[0];
  const float* emb  = (const float*)d_in[1];
  const float* Wx0  = (const float*)d_in[2];
  const float* Wh0  = (const float*)d_in[3];
  const float* b0   = (const float*)d_in[4];
  const float* Wx1  = (const float*)d_in[5];
  const float* Wh1  = (const float*)d_in[6];
  const float* b1   = (const float*)d_in[7];
  const float* Wx2  = (const float*)d_in[8];
  const float* Wh2  = (const float*)d_in[9];
  const float* b2   = (const float*)d_in[10];
  const float* Wout = (const float*)d_in[11];
  const float* bout = (const float*)d_in[12];

  char* ws = (char*)d_ws;
  float* proj = (float*)ws;                                   // 10000*512*4  = 20.48 MB
  unsigned short* Wh0t = (unsigned short*)(ws + (size_t)TW * U * 4);
  unsigned short* W1t  = Wh0t + (size_t)U * U;                // [512][1024]
  unsigned short* W2t  = W1t  + (size_t)U * 2 * U;

  proj_kernel<<<TW / 16, 256, 0, stream>>>(emb, Wx0, b0, proj);
  const int tblk = (U * U + 255) / 256;
  transpose_bf16<<<tblk, 256, 0, stream>>>(Wh0, Wh0t, U, U, U,     0);
  transpose_bf16<<<tblk, 256, 0, stream>>>(Wx1, W1t,  U, U, 2 * U, 0);
  transpose_bf16<<<tblk, 256, 0, stream>>>(Wh1, W1t,  U, U, 2 * U, U);
  transpose_bf16<<<tblk, 256, 0, stream>>>(Wx2, W2t,  U, U, 2 * U, 0);
  transpose_bf16<<<tblk, 256, 0, stream>>>(Wh2, W2t,  U, U, 2 * U, U);

  rnn_persist<<<NBLK, NTHR, 0, stream>>>(tokens, proj, Wh0t, W1t, W2t,
                                         b1, b2, Wout, bout, (float*)d_out);
}